// Round 1
// baseline (959.280 us; speedup 1.0000x reference)
//
#include <hip/hip_runtime.h>
#include <math.h>

#define NN 100000
#define NE 3200000
#define FIN 256
#define HID 16
#define NC 32

// ---------------------------------------------------------------------------
// K1: fused node GEMM for layer 1.
//   xs1[n][0..15]  = x[n] @ W1[0]        (interleaved per node: 32 floats)
//   xs1[n][16..31] = x[n] @ W1[1]
//   r1[n][0..15]   = x[n] @ root1 + bias1
// Combined weight block (256 x 48) staged in LDS; 2 nodes per thread so the
// FMA : ds_read_b128 ratio is 8:1.
// ---------------------------------------------------------------------------
__global__ __launch_bounds__(256) void k_gemm1(
    const float* __restrict__ x, const float* __restrict__ W1,
    const float* __restrict__ root1, const float* __restrict__ bias1,
    float* __restrict__ xs1, float* __restrict__ r1)
{
    __shared__ float w[FIN * 48];   // 48 KiB
    for (int i = threadIdx.x; i < FIN * 48; i += 256) {
        int f = i / 48, j = i - f * 48;
        float v;
        if (j < 16)      v = W1[f * 16 + j];                   // W1[0][f][j]
        else if (j < 32) v = W1[FIN * 16 + f * 16 + (j - 16)]; // W1[1][f][j-16]
        else             v = root1[f * 16 + (j - 32)];         // root1[f][j-32]
        w[i] = v;
    }
    __syncthreads();

    int n0 = blockIdx.x * 512 + threadIdx.x;
    int n1 = n0 + 256;
    bool p0 = n0 < NN, p1 = n1 < NN;
    const float4* x0 = (const float4*)(x + (size_t)(p0 ? n0 : 0) * FIN);
    const float4* x1 = (const float4*)(x + (size_t)(p1 ? n1 : 0) * FIN);

    float acc0[48], acc1[48];
    #pragma unroll
    for (int o = 0; o < 48; ++o) { acc0[o] = 0.f; acc1[o] = 0.f; }

    const float4* wv = (const float4*)w;   // row stride = 12 float4
    for (int q = 0; q < FIN / 4; ++q) {
        float4 a = x0[q];
        float4 b = x1[q];
        int base = q * 48;                 // float4 index of row f=4q
        #pragma unroll
        for (int j = 0; j < 12; ++j) {
            float4 w0 = wv[base + j];
            float4 w1r = wv[base + 12 + j];
            float4 w2 = wv[base + 24 + j];
            float4 w3 = wv[base + 36 + j];
            int o = j * 4;
            acc0[o+0] += a.x*w0.x + a.y*w1r.x + a.z*w2.x + a.w*w3.x;
            acc0[o+1] += a.x*w0.y + a.y*w1r.y + a.z*w2.y + a.w*w3.y;
            acc0[o+2] += a.x*w0.z + a.y*w1r.z + a.z*w2.z + a.w*w3.z;
            acc0[o+3] += a.x*w0.w + a.y*w1r.w + a.z*w2.w + a.w*w3.w;
            acc1[o+0] += b.x*w0.x + b.y*w1r.x + b.z*w2.x + b.w*w3.x;
            acc1[o+1] += b.x*w0.y + b.y*w1r.y + b.z*w2.y + b.w*w3.y;
            acc1[o+2] += b.x*w0.z + b.y*w1r.z + b.z*w2.z + b.w*w3.z;
            acc1[o+3] += b.x*w0.w + b.y*w1r.w + b.z*w2.w + b.w*w3.w;
        }
    }
    if (p0) {
        float* xs = xs1 + (size_t)n0 * 32;
        float* rr = r1 + (size_t)n0 * 16;
        #pragma unroll
        for (int o = 0; o < 32; ++o) xs[o] = acc0[o];
        #pragma unroll
        for (int o = 0; o < 16; ++o) rr[o] = acc0[32 + o] + bias1[o];
    }
    if (p1) {
        float* xs = xs1 + (size_t)n1 * 32;
        float* rr = r1 + (size_t)n1 * 16;
        #pragma unroll
        for (int o = 0; o < 32; ++o) xs[o] = acc1[o];
        #pragma unroll
        for (int o = 0; o < 16; ++o) rr[o] = acc1[32 + o] + bias1[o];
    }
}

// ---------------------------------------------------------------------------
// K2: layer-1 edge kernel. 16 lanes per edge (c = channel).
// msg = (1-u)*xs0[src][c] + u*xs1[src][c]; atomicAdd into agg1[dst][c].
// Lane c==0 also accumulates the in-degree count.
// ---------------------------------------------------------------------------
__global__ __launch_bounds__(256) void k_edge1(
    const int* __restrict__ ei, const float* __restrict__ ea,
    const float* __restrict__ xs1, float* __restrict__ agg1,
    float* __restrict__ cnt)
{
    int gid = blockIdx.x * 256 + threadIdx.x;   // < 51.2M
    int e = gid >> 4;
    int c = gid & 15;
    if (e >= NE) return;
    int src = ei[e];
    int dst = ei[NE + e];
    float u = ea[e];
    u = fminf(fmaxf(u, 0.f), 1.f);
    const float* xp = xs1 + (size_t)src * 32;
    float msg = (1.f - u) * xp[c] + u * xp[16 + c];
    atomicAdd(&agg1[(size_t)dst * 16 + c], msg);
    if (c == 0) atomicAdd(&cnt[dst], 1.f);
}

// ---------------------------------------------------------------------------
// K3: h = elu(agg1/max(cnt,1) + r1)   (in place over r1 buffer)
// ---------------------------------------------------------------------------
__global__ __launch_bounds__(256) void k_h(
    const float* __restrict__ agg1, const float* __restrict__ cnt,
    float* __restrict__ r1h)
{
    int i = blockIdx.x * 256 + threadIdx.x;
    if (i >= NN * HID) return;
    int n = i >> 4;
    float inv = 1.f / fmaxf(cnt[n], 1.f);
    float v = agg1[i] * inv + r1h[i];
    r1h[i] = v > 0.f ? v : expm1f(v);
}

// ---------------------------------------------------------------------------
// K4: layer-2 node GEMM. 96 outputs per node:
//   c in [0,32):  hs2[n*64+c]    = h[n] @ W2[0][:, c]
//   c in [32,64): hs2[n*64+c]    = h[n] @ W2[1][:, c-32]
//   c in [64,96): r2[n*32+c-64]  = h[n] @ root2[:, c-64] + bias2[c-64]
// ---------------------------------------------------------------------------
__global__ __launch_bounds__(256) void k_gemm2(
    const float* __restrict__ h, const float* __restrict__ W2,
    const float* __restrict__ root2, const float* __restrict__ bias2,
    float* __restrict__ hs2, float* __restrict__ r2)
{
    int gid = blockIdx.x * 256 + threadIdx.x;
    if (gid >= NN * 96) return;
    int n = gid / 96;
    int c = gid - n * 96;
    const float* hp = h + (size_t)n * HID;
    float hv[HID];
    #pragma unroll
    for (int k = 0; k < HID; ++k) hv[k] = hp[k];

    if (c < 64) {
        int km = c >> 5;
        int o  = c & 31;
        const float* wq = W2 + km * (HID * NC) + o;   // stride NC over k
        float acc = 0.f;
        #pragma unroll
        for (int k = 0; k < HID; ++k) acc += hv[k] * wq[k * NC];
        hs2[(size_t)n * 64 + c] = acc;
    } else {
        int o = c - 64;
        const float* wq = root2 + o;
        float acc = bias2[o];
        #pragma unroll
        for (int k = 0; k < HID; ++k) acc += hv[k] * wq[k * NC];
        r2[(size_t)n * NC + o] = acc;
    }
}

// ---------------------------------------------------------------------------
// K5: layer-2 edge kernel. 32 lanes per edge.
// ---------------------------------------------------------------------------
__global__ __launch_bounds__(256) void k_edge2(
    const int* __restrict__ ei, const float* __restrict__ ea,
    const float* __restrict__ hs2, float* __restrict__ agg2)
{
    int gid = blockIdx.x * 256 + threadIdx.x;   // < 102.4M
    int e = gid >> 5;
    int c = gid & 31;
    if (e >= NE) return;
    int src = ei[e];
    int dst = ei[NE + e];
    float u = ea[e];
    u = fminf(fmaxf(u, 0.f), 1.f);
    const float* hp = hs2 + (size_t)src * 64;
    float msg = (1.f - u) * hp[c] + u * hp[32 + c];
    atomicAdd(&agg2[(size_t)dst * NC + c], msg);
}

// ---------------------------------------------------------------------------
// K6: out = log_softmax(agg2/max(cnt,1) + r2), in place over agg2 (= d_out).
// 32 lanes per node; width-32 shuffles for max / sum.
// ---------------------------------------------------------------------------
__global__ __launch_bounds__(256) void k_out(
    const float* __restrict__ r2, const float* __restrict__ cnt,
    float* __restrict__ out)
{
    int gid = blockIdx.x * 256 + threadIdx.x;
    if (gid >= NN * NC) return;
    int n = gid >> 5;
    float inv = 1.f / fmaxf(cnt[n], 1.f);
    float v = out[gid] * inv + r2[gid];

    float m = v;
    #pragma unroll
    for (int off = 16; off > 0; off >>= 1)
        m = fmaxf(m, __shfl_xor(m, off, 32));
    float s = expf(v - m);
    #pragma unroll
    for (int off = 16; off > 0; off >>= 1)
        s += __shfl_xor(s, off, 32);
    out[gid] = v - m - logf(s);
}

// ---------------------------------------------------------------------------
extern "C" void kernel_launch(void* const* d_in, const int* in_sizes, int n_in,
                              void* d_out, int out_size, void* d_ws, size_t ws_size,
                              hipStream_t stream)
{
    const float* x     = (const float*)d_in[0];
    const float* ea    = (const float*)d_in[1];
    const float* W1    = (const float*)d_in[2];
    const float* root1 = (const float*)d_in[3];
    const float* bias1 = (const float*)d_in[4];
    const float* W2    = (const float*)d_in[5];
    const float* root2 = (const float*)d_in[6];
    const float* bias2 = (const float*)d_in[7];
    const int*   ei    = (const int*)d_in[8];
    float* out = (float*)d_out;

    // Workspace layout (floats): total NN*161 = 64.4 MB
    float* ws   = (float*)d_ws;
    float* xs1  = ws;                        // NN*32  (interleaved xs0|xs1)
    float* r1h  = ws + (size_t)NN * 32;      // NN*16  (r1, then h in place)
    float* agg1 = ws + (size_t)NN * 48;      // NN*16
    float* cnt  = ws + (size_t)NN * 64;      // NN
    float* hs2  = ws + (size_t)NN * 65;      // NN*64  (interleaved hs0|hs1)
    float* r2   = ws + (size_t)NN * 129;     // NN*32

    // Zero the accumulators (ws/out are poisoned before every call).
    hipMemsetAsync(agg1, 0, (size_t)NN * 17 * sizeof(float), stream); // agg1+cnt
    hipMemsetAsync(out, 0, (size_t)NN * NC * sizeof(float), stream);  // agg2

    k_gemm1<<<(NN + 511) / 512, 256, 0, stream>>>(x, W1, root1, bias1, xs1, r1h);
    k_edge1<<<(NE * 16) / 256, 256, 0, stream>>>(ei, ea, xs1, agg1, cnt);
    k_h<<<(NN * HID + 255) / 256, 256, 0, stream>>>(agg1, cnt, r1h);
    k_gemm2<<<(NN * 96 + 255) / 256, 256, 0, stream>>>(r1h, W2, root2, bias2, hs2, r2);
    k_edge2<<<(NE * 32) / 256, 256, 0, stream>>>(ei, ea, hs2, out);
    k_out<<<(NN * NC + 255) / 256, 256, 0, stream>>>(r2, cnt, out);
}

// Round 3
// 790.713 us; speedup vs baseline: 1.2132x; 1.2132x over previous
//
#include <hip/hip_runtime.h>
#include <hip/hip_fp16.h>
#include <math.h>

#define NN 100000
#define NE 3200000
#define FIN 256
#define HID 16
#define NC 32
#define NB 391   // (NN+255)/256 scan blocks

// ---------------------------------------------------------------------------
// K1: fused node GEMM for layer 1.
//   xs1p[n*16+c] = half2( x[n]@W1[0][:,c], x[n]@W1[1][:,c] )  c=0..15 (64 B/node)
//   r1[n*16+c]   = x[n]@root1[:,c] + bias1[c]                 (fp32)
// ---------------------------------------------------------------------------
__global__ __launch_bounds__(256) void k_gemm1(
    const float* __restrict__ x, const float* __restrict__ W1,
    const float* __restrict__ root1, const float* __restrict__ bias1,
    __half2* __restrict__ xs1p, float* __restrict__ r1)
{
    __shared__ float w[FIN * 48];   // 48 KiB
    for (int i = threadIdx.x; i < FIN * 48; i += 256) {
        int f = i / 48, j = i - f * 48;
        float v;
        if (j < 16)      v = W1[f * 16 + j];                   // W1[0][f][j]
        else if (j < 32) v = W1[FIN * 16 + f * 16 + (j - 16)]; // W1[1][f][j-16]
        else             v = root1[f * 16 + (j - 32)];         // root1[f][j-32]
        w[i] = v;
    }
    __syncthreads();

    int n0 = blockIdx.x * 512 + threadIdx.x;
    int n1 = n0 + 256;
    bool p0 = n0 < NN, p1 = n1 < NN;
    const float4* x0 = (const float4*)(x + (size_t)(p0 ? n0 : 0) * FIN);
    const float4* x1 = (const float4*)(x + (size_t)(p1 ? n1 : 0) * FIN);

    float acc0[48], acc1[48];
    #pragma unroll
    for (int o = 0; o < 48; ++o) { acc0[o] = 0.f; acc1[o] = 0.f; }

    const float4* wv = (const float4*)w;   // row stride = 12 float4
    for (int q = 0; q < FIN / 4; ++q) {
        float4 a = x0[q];
        float4 b = x1[q];
        int base = q * 48;
        #pragma unroll
        for (int j = 0; j < 12; ++j) {
            float4 w0 = wv[base + j];
            float4 w1r = wv[base + 12 + j];
            float4 w2 = wv[base + 24 + j];
            float4 w3 = wv[base + 36 + j];
            int o = j * 4;
            acc0[o+0] += a.x*w0.x + a.y*w1r.x + a.z*w2.x + a.w*w3.x;
            acc0[o+1] += a.x*w0.y + a.y*w1r.y + a.z*w2.y + a.w*w3.y;
            acc0[o+2] += a.x*w0.z + a.y*w1r.z + a.z*w2.z + a.w*w3.z;
            acc0[o+3] += a.x*w0.w + a.y*w1r.w + a.z*w2.w + a.w*w3.w;
            acc1[o+0] += b.x*w0.x + b.y*w1r.x + b.z*w2.x + b.w*w3.x;
            acc1[o+1] += b.x*w0.y + b.y*w1r.y + b.z*w2.y + b.w*w3.y;
            acc1[o+2] += b.x*w0.z + b.y*w1r.z + b.z*w2.z + b.w*w3.z;
            acc1[o+3] += b.x*w0.w + b.y*w1r.w + b.z*w2.w + b.w*w3.w;
        }
    }
    if (p0) {
        __half2* xs = xs1p + (size_t)n0 * 16;
        float* rr = r1 + (size_t)n0 * 16;
        #pragma unroll
        for (int c = 0; c < 16; ++c) xs[c] = __floats2half2_rn(acc0[c], acc0[16 + c]);
        #pragma unroll
        for (int c = 0; c < 16; ++c) rr[c] = acc0[32 + c] + bias1[c];
    }
    if (p1) {
        __half2* xs = xs1p + (size_t)n1 * 16;
        float* rr = r1 + (size_t)n1 * 16;
        #pragma unroll
        for (int c = 0; c < 16; ++c) xs[c] = __floats2half2_rn(acc1[c], acc1[16 + c]);
        #pragma unroll
        for (int c = 0; c < 16; ++c) rr[c] = acc1[32 + c] + bias1[c];
    }
}

// ---------------------------------------------------------------------------
// CSR build: histogram -> block scan (A,B,C) -> scatter (src,u) records.
// ---------------------------------------------------------------------------
__global__ __launch_bounds__(256) void k_hist(const int* __restrict__ ei,
                                              int* __restrict__ deg)
{
    int e = blockIdx.x * 256 + threadIdx.x;
    if (e < NE) atomicAdd(&deg[ei[NE + e]], 1);
}

__global__ __launch_bounds__(256) void k_scanA(const int* __restrict__ deg,
                                               int* __restrict__ incl,
                                               int* __restrict__ bsum)
{
    __shared__ int s[256];
    int t = threadIdx.x;
    int i = blockIdx.x * 256 + t;
    s[t] = (i < NN) ? deg[i] : 0;
    __syncthreads();
    for (int off = 1; off < 256; off <<= 1) {
        int add = (t >= off) ? s[t - off] : 0;
        __syncthreads();
        s[t] += add;
        __syncthreads();
    }
    if (i < NN) incl[i] = s[t];
    if (t == 255) bsum[blockIdx.x] = s[255];
}

__global__ __launch_bounds__(512) void k_scanB(const int* __restrict__ bsum,
                                               int* __restrict__ binc)
{
    __shared__ int s[512];
    int t = threadIdx.x;
    s[t] = (t < NB) ? bsum[t] : 0;
    __syncthreads();
    for (int off = 1; off < 512; off <<= 1) {
        int add = (t >= off) ? s[t - off] : 0;
        __syncthreads();
        s[t] += add;
        __syncthreads();
    }
    if (t < NB) binc[t] = s[t];
}

__global__ __launch_bounds__(256) void k_scanC(
    const int* __restrict__ deg, const int* __restrict__ incl,
    const int* __restrict__ binc, int* __restrict__ rowptr,
    int* __restrict__ cursor)
{
    int i = blockIdx.x * 256 + threadIdx.x;
    if (i >= NN) return;
    int blk = i >> 8;
    int base = blk ? binc[blk - 1] : 0;
    int rp = base + incl[i] - deg[i];   // exclusive prefix
    rowptr[i] = rp;
    cursor[i] = rp;
}

__global__ __launch_bounds__(256) void k_scatter(
    const int* __restrict__ ei, const float* __restrict__ ea,
    int* __restrict__ cursor, int* __restrict__ esrc, __half* __restrict__ eu)
{
    int e = blockIdx.x * 256 + threadIdx.x;
    if (e >= NE) return;
    int src = ei[e];
    int dst = ei[NE + e];
    float u = fminf(fmaxf(ea[e], 0.f), 1.f);
    int pos = atomicAdd(&cursor[dst], 1);
    esrc[pos] = src;
    eu[pos] = __float2half(u);
}

// ---------------------------------------------------------------------------
// K_agg1: gather-only layer-1 aggregation, fused mean + root + ELU.
// 8 lanes per node; lane j owns channels 2j, 2j+1. fp32 accumulation.
// Writes h in place over r1 (each element read+written by its own thread).
// ---------------------------------------------------------------------------
__global__ __launch_bounds__(256) void k_agg1(
    const int* __restrict__ rowptr, const int* __restrict__ deg,
    const int* __restrict__ esrc, const __half* __restrict__ eu,
    const uint2* __restrict__ xs1p, float* __restrict__ r1h)
{
    int gid = blockIdx.x * 256 + threadIdx.x;   // NN*8 exact
    int n = gid >> 3, j = gid & 7;
    if (n >= NN) return;
    int s = rowptr[n], d = deg[n];
    float a0 = 0.f, a1 = 0.f;
    for (int k = 0; k < d; ++k) {
        int e = s + k;
        int src = esrc[e];
        float u = __half2float(eu[e]);
        uint2 pv = xs1p[(size_t)src * 8 + j];   // half2 pair: ch 2j, 2j+1
        float2 f0 = __half22float2(*(const __half2*)&pv.x);
        float2 f1 = __half22float2(*(const __half2*)&pv.y);
        a0 += (1.f - u) * f0.x + u * f0.y;
        a1 += (1.f - u) * f1.x + u * f1.y;
    }
    float inv = 1.f / fmaxf((float)d, 1.f);
    float2 r = ((const float2*)r1h)[(size_t)n * 8 + j];
    float v0 = a0 * inv + r.x;
    float v1 = a1 * inv + r.y;
    v0 = v0 > 0.f ? v0 : expm1f(v0);
    v1 = v1 > 0.f ? v1 : expm1f(v1);
    ((float2*)r1h)[(size_t)n * 8 + j] = make_float2(v0, v1);
}

// ---------------------------------------------------------------------------
// K_gemm2: layer-2 node GEMM. 64 threads per node.
// ---------------------------------------------------------------------------
__global__ __launch_bounds__(256) void k_gemm2(
    const float* __restrict__ h, const float* __restrict__ W2,
    const float* __restrict__ root2, const float* __restrict__ bias2,
    __half2* __restrict__ hs2p, float* __restrict__ r2)
{
    int gid = blockIdx.x * 256 + threadIdx.x;   // NN*64 exact
    int n = gid >> 6;
    int t = gid & 63;
    if (n >= NN) return;
    const float* hp = h + (size_t)n * HID;
    float hv[HID];
    #pragma unroll
    for (int k = 0; k < HID; ++k) hv[k] = hp[k];

    if (t < 32) {
        float d0 = 0.f, d1 = 0.f;
        #pragma unroll
        for (int k = 0; k < HID; ++k) {
            d0 += hv[k] * W2[k * NC + t];
            d1 += hv[k] * W2[HID * NC + k * NC + t];
        }
        hs2p[(size_t)n * 32 + t] = __floats2half2_rn(d0, d1);
    } else {
        int c = t - 32;
        float acc = bias2[c];
        #pragma unroll
        for (int k = 0; k < HID; ++k) acc += hv[k] * root2[k * NC + c];
        r2[(size_t)n * NC + c] = acc;
    }
}

// ---------------------------------------------------------------------------
// K_agg2: gather-only layer-2 aggregation, fused mean + root + log_softmax.
// 16 lanes per node; lane j owns channels 2j, 2j+1. fp32 accumulation.
// Writes d_out directly.
// ---------------------------------------------------------------------------
__global__ __launch_bounds__(256) void k_agg2(
    const int* __restrict__ rowptr, const int* __restrict__ deg,
    const int* __restrict__ esrc, const __half* __restrict__ eu,
    const uint2* __restrict__ hs2p, const float* __restrict__ r2,
    float* __restrict__ out)
{
    int gid = blockIdx.x * 256 + threadIdx.x;   // NN*16 exact
    int n = gid >> 4, j = gid & 15;
    if (n >= NN) return;
    int s = rowptr[n], d = deg[n];
    float a0 = 0.f, a1 = 0.f;
    for (int k = 0; k < d; ++k) {
        int e = s + k;
        int src = esrc[e];
        float u = __half2float(eu[e]);
        uint2 pv = hs2p[(size_t)src * 16 + j];
        float2 f0 = __half22float2(*(const __half2*)&pv.x);
        float2 f1 = __half22float2(*(const __half2*)&pv.y);
        a0 += (1.f - u) * f0.x + u * f0.y;
        a1 += (1.f - u) * f1.x + u * f1.y;
    }
    float inv = 1.f / fmaxf((float)d, 1.f);
    float2 r = ((const float2*)r2)[(size_t)n * 16 + j];
    float v0 = a0 * inv + r.x;
    float v1 = a1 * inv + r.y;

    float m = fmaxf(v0, v1);
    #pragma unroll
    for (int off = 1; off < 16; off <<= 1)
        m = fmaxf(m, __shfl_xor(m, off, 16));
    float sm = expf(v0 - m) + expf(v1 - m);
    #pragma unroll
    for (int off = 1; off < 16; off <<= 1)
        sm += __shfl_xor(sm, off, 16);
    float ls = logf(sm);
    ((float2*)out)[(size_t)n * 16 + j] = make_float2(v0 - m - ls, v1 - m - ls);
}

// ---------------------------------------------------------------------------
extern "C" void kernel_launch(void* const* d_in, const int* in_sizes, int n_in,
                              void* d_out, int out_size, void* d_ws, size_t ws_size,
                              hipStream_t stream)
{
    const float* x     = (const float*)d_in[0];
    const float* ea    = (const float*)d_in[1];
    const float* W1    = (const float*)d_in[2];
    const float* root1 = (const float*)d_in[3];
    const float* bias1 = (const float*)d_in[4];
    const float* W2    = (const float*)d_in[5];
    const float* root2 = (const float*)d_in[6];
    const float* bias2 = (const float*)d_in[7];
    const int*   ei    = (const int*)d_in[8];
    float* out = (float*)d_out;

    // Workspace layout (float units; half2 = 4 B = 1 float!):
    float* ws = (float*)d_ws;
    __half2* xs1p = (__half2*)ws;                      // NN*16 half2 = NN*16 fl
    float*   r1h  = ws + (size_t)NN * 16;              // NN*16 fl (r1, then h)
    __half2* hs2p = (__half2*)(ws + (size_t)NN * 32);  // NN*32 half2 = NN*32 fl
    float*   r2   = ws + (size_t)NN * 64;              // NN*32 fl
    int*     esrc = (int*)(ws + (size_t)NN * 96);      // NE ints  = NN*32 fl
    __half*  eu   = (__half*)(ws + (size_t)NN * 128);  // NE half  = NN*16 fl
    int*     iws  = (int*)(ws + (size_t)NN * 144);
    int* deg    = iws;            // NN
    int* incl   = iws + NN;       // NN
    int* rowptr = iws + 2 * NN;   // NN
    int* cursor = iws + 3 * NN;   // NN
    int* bsum   = iws + 4 * NN;   // 512
    int* binc   = bsum + 512;     // 512
    // total = NN*148 floats + 4 KB ≈ 59.2 MB

    hipMemsetAsync(deg, 0, (size_t)NN * sizeof(int), stream);

    k_gemm1<<<(NN + 511) / 512, 256, 0, stream>>>(x, W1, root1, bias1, xs1p, r1h);
    k_hist<<<(NE + 255) / 256, 256, 0, stream>>>(ei, deg);
    k_scanA<<<NB, 256, 0, stream>>>(deg, incl, bsum);
    k_scanB<<<1, 512, 0, stream>>>(bsum, binc);
    k_scanC<<<NB, 256, 0, stream>>>(deg, incl, binc, rowptr, cursor);
    k_scatter<<<(NE + 255) / 256, 256, 0, stream>>>(ei, ea, cursor, esrc, eu);
    k_agg1<<<(NN * 8 + 255) / 256, 256, 0, stream>>>(rowptr, deg, esrc, eu,
                                                     (const uint2*)xs1p, r1h);
    k_gemm2<<<(NN * 64 + 255) / 256, 256, 0, stream>>>(r1h, W2, root2, bias2, hs2p, r2);
    k_agg2<<<(NN * 16 + 255) / 256, 256, 0, stream>>>(rowptr, deg, esrc, eu,
                                                      (const uint2*)hs2p, r2, out);
}